// Round 2
// baseline (3517.941 us; speedup 1.0000x reference)
//
#include <hip/hip_runtime.h>

typedef unsigned short u16;
typedef __bf16 bf16x8 __attribute__((ext_vector_type(8)));
typedef float f32x4 __attribute__((ext_vector_type(4)));
typedef unsigned short u16x4 __attribute__((ext_vector_type(4)));

__device__ __forceinline__ u16 f2bf(float f) {
  union { float f; unsigned int u; } v; v.f = f;
  return (u16)((v.u + 0x7FFFu + ((v.u >> 16) & 1u)) >> 16);
}

__device__ __forceinline__ void gload16(const void* g, void* l) {
  __builtin_amdgcn_global_load_lds(
      (const __attribute__((address_space(1))) unsigned int*)g,
      (__attribute__((address_space(3))) unsigned int*)l, 16, 0, 0);
}

// ---------------------------------------------------------------------------
// Weight prep
// ---------------------------------------------------------------------------

// W (R x C f32, per-layer stride R*C) -> WT (C x R bf16)
__global__ void transpose_cast_kernel(const float* __restrict__ W, u16* __restrict__ WT,
                                      int R, int C) {
  __shared__ float tile[32][33];
  const int tx = threadIdx.x, ty = threadIdx.y;
  const size_t zoff = (size_t)blockIdx.z * R * C;
  const int c0 = blockIdx.x * 32, r0 = blockIdx.y * 32;
#pragma unroll
  for (int k = 0; k < 32; k += 8)
    tile[ty + k][tx] = W[zoff + (size_t)(r0 + ty + k) * C + (c0 + tx)];
  __syncthreads();
#pragma unroll
  for (int k = 0; k < 32; k += 8)
    WT[zoff + (size_t)(c0 + ty + k) * R + (r0 + tx)] = f2bf(tile[tx][ty + k]);
}

// lm_head (50257 x 1024 f32) -> bf16 padded to 50304 rows (pad rows zero)
__global__ void lm_cast_kernel(const float* __restrict__ lm, u16* __restrict__ out) {
  const int row = blockIdx.x;
  const int t = threadIdx.x;
  u16x4 o = {0, 0, 0, 0};
  if (row < 50257) {
    float4 v = *(const float4*)(lm + (size_t)row * 1024 + t * 4);
    o.x = f2bf(v.x); o.y = f2bf(v.y); o.z = f2bf(v.z); o.w = f2bf(v.w);
  }
  *(u16x4*)(out + (size_t)row * 1024 + t * 4) = o;
}

// ---------------------------------------------------------------------------
// Embedding gather (f32 residual stream init)
// ---------------------------------------------------------------------------
__global__ void embed_kernel(const int* __restrict__ ids, const float* __restrict__ embed,
                             float* __restrict__ x) {
  const int row = blockIdx.x;
  const int id = ids[row];
  const int t = threadIdx.x;
  *(float4*)(x + (size_t)row * 1024 + t * 4) =
      *(const float4*)(embed + (size_t)id * 1024 + t * 4);
}

// ---------------------------------------------------------------------------
// RMSNorm: f32 in -> bf16 out (D = 1024, one block per row)
// ---------------------------------------------------------------------------
__global__ void rmsnorm_kernel(const float* __restrict__ x, const float* __restrict__ w,
                               u16* __restrict__ out) {
  const int row = blockIdx.x, tid = threadIdx.x;
  const float* xr = x + (size_t)row * 1024;
  float4 v = *(const float4*)(xr + tid * 4);
  float ss = v.x * v.x + v.y * v.y + v.z * v.z + v.w * v.w;
#pragma unroll
  for (int off = 32; off; off >>= 1) ss += __shfl_xor(ss, off);
  __shared__ float red[4];
  if ((tid & 63) == 0) red[tid >> 6] = ss;
  __syncthreads();
  const float tot = red[0] + red[1] + red[2] + red[3];
  const float r = rsqrtf(tot * (1.0f / 1024.0f) + 1e-6f);
  float4 wv = *(const float4*)(w + tid * 4);
  u16x4 o;
  o.x = f2bf(v.x * r * wv.x); o.y = f2bf(v.y * r * wv.y);
  o.z = f2bf(v.z * r * wv.z); o.w = f2bf(v.w * r * wv.w);
  *(u16x4*)(out + (size_t)row * 1024 + tid * 4) = o;
}

// ---------------------------------------------------------------------------
// Sequential chaotic scan: s_t = tanh(a*s_{t-1} + pre_t), hs bf16 out.
// 2048 independent chains (B*D); software-pipelined 4x8 register prefetch.
// Recurrence in r-space (s = 1-2r): 4-op dependent chain
//   z_t = fma(-2*A2, r_{t-1}, A2 + 2L*p_t); e = exp2(z); r_t = rcp(1+e)
// where A2 = 2*log2e*a. tanh reconstruction + store are off-chain.
// ---------------------------------------------------------------------------
__device__ __forceinline__ void scan_load(const float* __restrict__ p, int tb,
                                          float A2, float (&buf)[8]) {
#pragma unroll
  for (int j = 0; j < 8; j++)
    buf[j] = fmaf(p[(size_t)(tb + j) * 1024], 2.8853900817779268f, A2);
}

__device__ __forceinline__ void scan_comp(float (&buf)[8], float m2A2, float& r,
                                          u16* __restrict__ o, int tb) {
#pragma unroll
  for (int j = 0; j < 8; j++) {
    float z = fmaf(m2A2, r, buf[j]);
    float e = __builtin_amdgcn_exp2f(z);
    r = __builtin_amdgcn_rcpf(1.0f + e);
    o[(size_t)(tb + j) * 1024] = f2bf(fmaf(-2.0f, r, 1.0f));
  }
}

__global__ __launch_bounds__(256) void scan_kernel(const float* __restrict__ pre,
                                                   const float* __restrict__ a_diag,
                                                   u16* __restrict__ hs) {
  const int T = 2048;
  const int idx = blockIdx.x * 256 + threadIdx.x;  // 0..2047
  const int b = idx >> 10, d = idx & 1023;
  const float* p = pre + (size_t)b * T * 1024 + d;
  u16* o = hs + (size_t)b * T * 1024 + d;
  const float A2 = a_diag[d] * 2.8853900817779268f;
  const float m2A2 = -2.0f * A2;
  float r = 0.5f;  // s = 1 - 2r = 0
  float b0[8], b1[8], b2[8], b3[8];
  scan_load(p, 0, A2, b0); scan_load(p, 8, A2, b1);
  scan_load(p, 16, A2, b2); scan_load(p, 24, A2, b3);
  for (int t0 = 0; t0 < T; t0 += 32) {
    scan_comp(b0, m2A2, r, o, t0);
    if (t0 + 32 < T) scan_load(p, t0 + 32, A2, b0);
    scan_comp(b1, m2A2, r, o, t0 + 8);
    if (t0 + 32 < T) scan_load(p, t0 + 40, A2, b1);
    scan_comp(b2, m2A2, r, o, t0 + 16);
    if (t0 + 32 < T) scan_load(p, t0 + 48, A2, b2);
    scan_comp(b3, m2A2, r, o, t0 + 24);
    if (t0 + 32 < T) scan_load(p, t0 + 56, A2, b3);
  }
}

// ---------------------------------------------------------------------------
// NT bf16 GEMM: C(M x N) = A(M x K) @ B(N x K)^T  [both row-major, bf16]
// 128x128 tile, BK=32, 4 waves (2x2 of 64x64), mfma 16x16x32.
// LDS slot-swizzle: 16B slot ^= ((row>>1)&3) -> staging stays coalesced AND
// wave-wide ds_read_b128 touches 64 distinct 16B slots (conflict-free).
// EPI: 0 = f32 out + bias (scan pre); 1 = f32 out += v + bias (residual);
//      2 = bf16 out silu(v+bias); 3 = f32 out, col < Nreal guard (lm head)
// EPI 3 uses a flattened grid (12576 blocks) with bijective XCD swizzle so
// the 32 CUs of one XCD walk 32 row-tiles sharing ONE B col-tile (L2 reuse).
// ---------------------------------------------------------------------------
template <int EPI>
__global__ __launch_bounds__(256) void gemm_nt(
    const u16* __restrict__ A, const u16* __restrict__ Bw,
    const float* __restrict__ bias, float* Cf, u16* __restrict__ Cb,
    int M, int N, int K, int ldc, int Nreal) {
  __shared__ u16 As[128 * 32];
  __shared__ u16 Bs[128 * 32];
  const int tid = threadIdx.x;
  const int lane = tid & 63;
  const int wid = tid >> 6;
  const int wm = wid >> 1, wn = wid & 1;
  int tm, tn;
  if (EPI == 3) {
    // nwg = 32 * 393 = 12576; 12576 % 8 == 0 -> chunk = 1572 per XCD
    const int bid = blockIdx.x;
    const int wg = (bid & 7) * 1572 + (bid >> 3);
    tm = (wg & 31) * 128;   // row tile: fast dim -> 32 CUs of an XCD share B-tile
    tn = (wg >> 5) * 128;   // col tile (B panel row block)
  } else {
    tm = blockIdx.y * 128;
    tn = blockIdx.x * 128;
  }

  // staging: chunk tid -> row tid>>2 (of 64), slot (tid&3)^((row>>1)&3); pass2 = +64 rows
  const size_t sA = (size_t)K * 2;  // row stride in bytes for A and B
  const int r0 = tid >> 2;
  const int slot = (tid & 3) ^ ((tid >> 3) & 3);
  const char* pA = (const char*)A + (size_t)(tm + r0) * sA + (slot << 4);
  const char* pB = (const char*)Bw + (size_t)(tn + r0) * sA + (slot << 4);
  const size_t rowskip = 64 * sA;
  char* dA0 = (char*)As + tid * 16;
  char* dB0 = (char*)Bs + tid * 16;

  // fragment read addresses (fixed across K loop)
  const int lr = lane & 15;
  const int rdoff = (((lane >> 4) << 4)) ^ ((((lr >> 1) & 3)) << 4);
  const char* aAddr[4];
  const char* bAddr[4];
#pragma unroll
  for (int m = 0; m < 4; m++)
    aAddr[m] = (const char*)As + (wm * 64 + m * 16 + lr) * 64 + rdoff;
#pragma unroll
  for (int n = 0; n < 4; n++)
    bAddr[n] = (const char*)Bs + (wn * 64 + n * 16 + lr) * 64 + rdoff;

  f32x4 acc[4][4] = {};

  for (int k0 = 0; k0 < K; k0 += 32) {
    const size_t kb = (size_t)k0 * 2;
    gload16(pA + kb, dA0);
    gload16(pA + rowskip + kb, dA0 + 4096);
    gload16(pB + kb, dB0);
    gload16(pB + rowskip + kb, dB0 + 4096);
    __syncthreads();
    bf16x8 af[4], bfr[4];
#pragma unroll
    for (int m = 0; m < 4; m++) af[m] = *(const bf16x8*)aAddr[m];
#pragma unroll
    for (int n = 0; n < 4; n++) bfr[n] = *(const bf16x8*)bAddr[n];
#pragma unroll
    for (int m = 0; m < 4; m++)
#pragma unroll
      for (int n = 0; n < 4; n++)
        acc[m][n] =
            __builtin_amdgcn_mfma_f32_16x16x32_bf16(af[m], bfr[n], acc[m][n], 0, 0, 0);
    __syncthreads();
  }

  // C/D layout: col = lane&15, row = (lane>>4)*4 + j   [m89/m91 verified]
  const int crow = tm + wm * 64 + ((lane >> 4) << 2);
  const int ccol = tn + wn * 64 + lr;
#pragma unroll
  for (int m = 0; m < 4; m++) {
#pragma unroll
    for (int n = 0; n < 4; n++) {
      const int cg = ccol + n * 16;
      float bb = 0.0f;
      if (EPI != 3) bb = bias ? bias[cg] : 0.0f;
#pragma unroll
      for (int j = 0; j < 4; j++) {
        const size_t off = (size_t)(crow + m * 16 + j) * ldc + cg;
        const float v = acc[m][n][j] + bb;
        if (EPI == 0) {
          Cf[off] = v;
        } else if (EPI == 1) {
          Cf[off] += v;
        } else if (EPI == 2) {
          const float sg = __builtin_amdgcn_rcpf(
              1.0f + __builtin_amdgcn_exp2f(-1.4426950408889634f * v));
          Cb[off] = f2bf(v * sg);
        } else {
          if (cg < Nreal) Cf[off] = v;
        }
      }
    }
  }
}

// ---------------------------------------------------------------------------
// Host
// ---------------------------------------------------------------------------
extern "C" void kernel_launch(void* const* d_in, const int* in_sizes, int n_in,
                              void* d_out, int out_size, void* d_ws, size_t ws_size,
                              hipStream_t stream) {
  const int T = 2048, D = 1024, V = 50257, L = 8;
  const int M = 2 * T;       // 4096 rows
  const int Vpad = 50304;    // 393 * 128

  const int* ids = (const int*)d_in[0];
  const float* embed = (const float*)d_in[1];
  const float* norm1_w = (const float*)d_in[2];
  const float* norm2_w = (const float*)d_in[3];
  const float* a_diag = (const float*)d_in[4];
  const float* W_in = (const float*)d_in[5];
  const float* b_in = (const float*)d_in[6];
  const float* W_out = (const float*)d_in[7];
  const float* ff_w1 = (const float*)d_in[8];
  const float* ff_b1 = (const float*)d_in[9];
  const float* ff_w2 = (const float*)d_in[10];
  const float* ff_b2 = (const float*)d_in[11];
  const float* final_norm_w = (const float*)d_in[12];
  const float* lm_head_w = (const float*)d_in[13];

  // workspace carve-up
  char* w = (char*)d_ws;
  float* x = (float*)w;      w += (size_t)M * D * 4;        // f32 residual
  u16* h = (u16*)w;          w += (size_t)M * D * 2;        // bf16 norm out
  float* pre = (float*)w;    w += (size_t)M * D * 4;        // f32 scan input
  u16* hs = (u16*)w;         w += (size_t)M * D * 2;        // bf16 scan out
  u16* hff = (u16*)w;        w += (size_t)M * 2 * D * 2;    // bf16 FF mid
  u16* WinT = (u16*)w;       w += (size_t)L * D * D * 2;
  u16* WoutT = (u16*)w;      w += (size_t)L * D * D * 2;
  u16* ffw1T = (u16*)w;      w += (size_t)L * 2 * D * D * 2;
  u16* ffw2T = (u16*)w;      w += (size_t)L * 2 * D * D * 2;
  u16* lmpad = (u16*)w;      w += (size_t)Vpad * D * 2;

  // ---- weight prep (deterministic, every call) ----
  lm_cast_kernel<<<Vpad, 256, 0, stream>>>(lm_head_w, lmpad);
  transpose_cast_kernel<<<dim3(32, 32, L), dim3(32, 8), 0, stream>>>(W_in, WinT, D, D);
  transpose_cast_kernel<<<dim3(32, 32, L), dim3(32, 8), 0, stream>>>(W_out, WoutT, D, D);
  transpose_cast_kernel<<<dim3(64, 32, L), dim3(32, 8), 0, stream>>>(ff_w1, ffw1T, D, 2 * D);
  transpose_cast_kernel<<<dim3(32, 64, L), dim3(32, 8), 0, stream>>>(ff_w2, ffw2T, 2 * D, D);

  // ---- embedding ----
  embed_kernel<<<M, 256, 0, stream>>>(ids, embed, x);

  // ---- layers ----
  for (int l = 0; l < L; l++) {
    rmsnorm_kernel<<<M, 256, 0, stream>>>(x, norm1_w + (size_t)l * D, h);
    gemm_nt<0><<<dim3(8, 32), 256, 0, stream>>>(
        h, WinT + (size_t)l * D * D, b_in + (size_t)l * D, pre, nullptr,
        M, D, D, D, D);
    scan_kernel<<<8, 256, 0, stream>>>(pre, a_diag + (size_t)l * D, hs);
    gemm_nt<1><<<dim3(8, 32), 256, 0, stream>>>(
        hs, WoutT + (size_t)l * D * D, nullptr, x, nullptr,
        M, D, D, D, D);
    rmsnorm_kernel<<<M, 256, 0, stream>>>(x, norm2_w + (size_t)l * D, h);
    gemm_nt<2><<<dim3(16, 32), 256, 0, stream>>>(
        h, ffw1T + (size_t)l * 2 * D * D, ff_b1 + (size_t)l * 2 * D, nullptr, hff,
        M, 2 * D, D, 2 * D, 2 * D);
    gemm_nt<1><<<dim3(8, 32), 256, 0, stream>>>(
        hff, ffw2T + (size_t)l * 2 * D * D, ff_b2 + (size_t)l * D, x, nullptr,
        M, D, 2 * D, D, D);
  }

  // ---- final norm + lm head ----
  rmsnorm_kernel<<<M, 256, 0, stream>>>(x, final_norm_w, h);
  gemm_nt<3><<<dim3(12576), 256, 0, stream>>>(
      h, lmpad, nullptr, (float*)d_out, nullptr,
      M, Vpad, D, V, V);
}

// Round 3
// 3211.683 us; speedup vs baseline: 1.0954x; 1.0954x over previous
//
#include <hip/hip_runtime.h>

typedef unsigned short u16;
typedef __bf16 bf16x8 __attribute__((ext_vector_type(8)));
typedef float f32x4 __attribute__((ext_vector_type(4)));
typedef unsigned short u16x4 __attribute__((ext_vector_type(4)));

__device__ __forceinline__ u16 f2bf(float f) {
  union { float f; unsigned int u; } v; v.f = f;
  return (u16)((v.u + 0x7FFFu + ((v.u >> 16) & 1u)) >> 16);
}

__device__ __forceinline__ void gload16(const void* g, void* l) {
  __builtin_amdgcn_global_load_lds(
      (const __attribute__((address_space(1))) unsigned int*)g,
      (__attribute__((address_space(3))) unsigned int*)l, 16, 0, 0);
}

// ---------------------------------------------------------------------------
// Weight prep
// ---------------------------------------------------------------------------

// W (R x C f32, per-layer stride R*C) -> WT (C x R bf16)
__global__ void transpose_cast_kernel(const float* __restrict__ W, u16* __restrict__ WT,
                                      int R, int C) {
  __shared__ float tile[32][33];
  const int tx = threadIdx.x, ty = threadIdx.y;
  const size_t zoff = (size_t)blockIdx.z * R * C;
  const int c0 = blockIdx.x * 32, r0 = blockIdx.y * 32;
#pragma unroll
  for (int k = 0; k < 32; k += 8)
    tile[ty + k][tx] = W[zoff + (size_t)(r0 + ty + k) * C + (c0 + tx)];
  __syncthreads();
#pragma unroll
  for (int k = 0; k < 32; k += 8)
    WT[zoff + (size_t)(c0 + ty + k) * R + (r0 + tx)] = f2bf(tile[tx][ty + k]);
}

// lm_head (50257 x 1024 f32) -> bf16 padded to 50304 rows (pad rows zero)
__global__ void lm_cast_kernel(const float* __restrict__ lm, u16* __restrict__ out) {
  const int row = blockIdx.x;
  const int t = threadIdx.x;
  u16x4 o = {0, 0, 0, 0};
  if (row < 50257) {
    float4 v = *(const float4*)(lm + (size_t)row * 1024 + t * 4);
    o.x = f2bf(v.x); o.y = f2bf(v.y); o.z = f2bf(v.z); o.w = f2bf(v.w);
  }
  *(u16x4*)(out + (size_t)row * 1024 + t * 4) = o;
}

// ---------------------------------------------------------------------------
// Embedding gather (f32 residual stream init)
// ---------------------------------------------------------------------------
__global__ void embed_kernel(const int* __restrict__ ids, const float* __restrict__ embed,
                             float* __restrict__ x) {
  const int row = blockIdx.x;
  const int id = ids[row];
  const int t = threadIdx.x;
  *(float4*)(x + (size_t)row * 1024 + t * 4) =
      *(const float4*)(embed + (size_t)id * 1024 + t * 4);
}

// ---------------------------------------------------------------------------
// RMSNorm: f32 in -> bf16 out (D = 1024, one block per row)
// ---------------------------------------------------------------------------
__global__ void rmsnorm_kernel(const float* __restrict__ x, const float* __restrict__ w,
                               u16* __restrict__ out) {
  const int row = blockIdx.x, tid = threadIdx.x;
  const float* xr = x + (size_t)row * 1024;
  float4 v = *(const float4*)(xr + tid * 4);
  float ss = v.x * v.x + v.y * v.y + v.z * v.z + v.w * v.w;
#pragma unroll
  for (int off = 32; off; off >>= 1) ss += __shfl_xor(ss, off);
  __shared__ float red[4];
  if ((tid & 63) == 0) red[tid >> 6] = ss;
  __syncthreads();
  const float tot = red[0] + red[1] + red[2] + red[3];
  const float r = rsqrtf(tot * (1.0f / 1024.0f) + 1e-6f);
  float4 wv = *(const float4*)(w + tid * 4);
  u16x4 o;
  o.x = f2bf(v.x * r * wv.x); o.y = f2bf(v.y * r * wv.y);
  o.z = f2bf(v.z * r * wv.z); o.w = f2bf(v.w * r * wv.w);
  *(u16x4*)(out + (size_t)row * 1024 + tid * 4) = o;
}

// ---------------------------------------------------------------------------
// Sequential chaotic scan (unchanged; ~27 us/layer, latency-bound)
// ---------------------------------------------------------------------------
__device__ __forceinline__ void scan_load(const float* __restrict__ p, int tb,
                                          float A2, float (&buf)[8]) {
#pragma unroll
  for (int j = 0; j < 8; j++)
    buf[j] = fmaf(p[(size_t)(tb + j) * 1024], 2.8853900817779268f, A2);
}

__device__ __forceinline__ void scan_comp(float (&buf)[8], float m2A2, float& r,
                                          u16* __restrict__ o, int tb) {
#pragma unroll
  for (int j = 0; j < 8; j++) {
    float z = fmaf(m2A2, r, buf[j]);
    float e = __builtin_amdgcn_exp2f(z);
    r = __builtin_amdgcn_rcpf(1.0f + e);
    o[(size_t)(tb + j) * 1024] = f2bf(fmaf(-2.0f, r, 1.0f));
  }
}

__global__ __launch_bounds__(256) void scan_kernel(const float* __restrict__ pre,
                                                   const float* __restrict__ a_diag,
                                                   u16* __restrict__ hs) {
  const int T = 2048;
  const int idx = blockIdx.x * 256 + threadIdx.x;  // 0..2047
  const int b = idx >> 10, d = idx & 1023;
  const float* p = pre + (size_t)b * T * 1024 + d;
  u16* o = hs + (size_t)b * T * 1024 + d;
  const float A2 = a_diag[d] * 2.8853900817779268f;
  const float m2A2 = -2.0f * A2;
  float r = 0.5f;  // s = 1 - 2r = 0
  float b0[8], b1[8], b2[8], b3[8];
  scan_load(p, 0, A2, b0); scan_load(p, 8, A2, b1);
  scan_load(p, 16, A2, b2); scan_load(p, 24, A2, b3);
  for (int t0 = 0; t0 < T; t0 += 32) {
    scan_comp(b0, m2A2, r, o, t0);
    if (t0 + 32 < T) scan_load(p, t0 + 32, A2, b0);
    scan_comp(b1, m2A2, r, o, t0 + 8);
    if (t0 + 32 < T) scan_load(p, t0 + 40, A2, b1);
    scan_comp(b2, m2A2, r, o, t0 + 16);
    if (t0 + 32 < T) scan_load(p, t0 + 48, A2, b2);
    scan_comp(b3, m2A2, r, o, t0 + 24);
    if (t0 + 32 < T) scan_load(p, t0 + 56, A2, b3);
  }
}

// ---------------------------------------------------------------------------
// NT bf16 GEMM: C(M x N) = A(M x K) @ B(N x K)^T  [both row-major, bf16]
// 128x128 tile, BK=32, 4 waves (2x2 of 64x64), mfma 16x16x32.
// 2-PHASE double-buffered K-loop (T3 minimum): stage step t+1 into buf^1
// BEFORE computing step t; single __syncthreads per step (its implicit
// vmcnt(0) lands after ~400cy of ds_read+MFMA cover). Critical at 1 block/CU
// (layer GEMMs, grid=256) where no inter-block overlap hides load latency.
// LDS slot-swizzle: 16B slot ^= ((row>>1)&3) -> staging coalesced AND
// wave-wide ds_read_b128 conflict-free.
// EPI: 0 = f32 out + bias; 1 = f32 out += v + bias; 2 = bf16 out silu(v+bias);
//      3 = f32 out, col < Nreal guard (lm head)
// EPI 3 grid map: XCD x owns row tiles 4x..4x+3 (1MB A resident in its L2);
// col tiles walked slowly, synchronized across XCDs (B streams ~once via L3).
// ---------------------------------------------------------------------------
template <int EPI>
__global__ __launch_bounds__(256) void gemm_nt(
    const u16* __restrict__ A, const u16* __restrict__ Bw,
    const float* __restrict__ bias, float* Cf, u16* __restrict__ Cb,
    int M, int N, int K, int ldc, int Nreal) {
  __shared__ char lds[32768];  // [buf][A 8K | B 8K] x2
  const int tid = threadIdx.x;
  const int lane = tid & 63;
  const int wid = tid >> 6;
  const int wm = wid >> 1, wn = wid & 1;
  int tm, tn;
  if (EPI == 3) {
    // nwg = 12576 = 8 XCD * 4 rowtiles * 393 coltiles; HW round-robins bid%8.
    const int bid = blockIdx.x;
    const int xcd = bid & 7;
    const int i = bid >> 3;            // sequential within an XCD
    tm = (xcd * 4 + (i & 3)) * 128;    // 4 fixed row tiles per XCD
    tn = (i >> 2) * 128;               // col tile changes every 4 blocks
  } else {
    tm = blockIdx.y * 128;
    tn = blockIdx.x * 128;
  }

  // staging: thread tid -> row tid>>2 (of 64), slot (tid&3)^((row>>1)&3); pass2 = +64 rows
  const size_t sA = (size_t)K * 2;  // row stride in bytes for A and B
  const int r0 = tid >> 2;
  const int slot = (tid & 3) ^ ((tid >> 3) & 3);
  const char* pA = (const char*)A + (size_t)(tm + r0) * sA + (slot << 4);
  const char* pB = (const char*)Bw + (size_t)(tn + r0) * sA + (slot << 4);
  const size_t rowskip = 64 * sA;

  // fragment read offsets within a buffer (A at +0, B at +8192)
  const int lr = lane & 15;
  const int rdoff = ((lane >> 4) << 4) ^ (((lr >> 1) & 3) << 4);
  int aOff[4], bOff[4];
#pragma unroll
  for (int m = 0; m < 4; m++) aOff[m] = (wm * 64 + m * 16 + lr) * 64 + rdoff;
#pragma unroll
  for (int n = 0; n < 4; n++) bOff[n] = 8192 + (wn * 64 + n * 16 + lr) * 64 + rdoff;

  f32x4 acc[4][4] = {};

  // prologue: stage first K-step into buf 0
  {
    char* dA = lds + tid * 16;
    gload16(pA, dA);
    gload16(pA + rowskip, dA + 4096);
    gload16(pB, dA + 8192);
    gload16(pB + rowskip, dA + 12288);
  }
  __syncthreads();

  int cur = 0;
  for (int k0 = 0; k0 < K; k0 += 32) {
    if (k0 + 32 < K) {  // stage next step into the other buffer
      const size_t kb = (size_t)(k0 + 32) * 2;
      char* dA = lds + (cur ^ 1) * 16384 + tid * 16;
      gload16(pA + kb, dA);
      gload16(pA + rowskip + kb, dA + 4096);
      gload16(pB + kb, dA + 8192);
      gload16(pB + rowskip + kb, dA + 12288);
    }
    const char* base = lds + cur * 16384;
    bf16x8 af[4], bfr[4];
#pragma unroll
    for (int m = 0; m < 4; m++) af[m] = *(const bf16x8*)(base + aOff[m]);
#pragma unroll
    for (int n = 0; n < 4; n++) bfr[n] = *(const bf16x8*)(base + bOff[n]);
#pragma unroll
    for (int m = 0; m < 4; m++)
#pragma unroll
      for (int n = 0; n < 4; n++)
        acc[m][n] =
            __builtin_amdgcn_mfma_f32_16x16x32_bf16(af[m], bfr[n], acc[m][n], 0, 0, 0);
    __syncthreads();  // drains vmcnt(0)+lgkmcnt(0): next buf ready, cur reads done
    cur ^= 1;
  }

  // C/D layout: col = lane&15, row = (lane>>4)*4 + j   [m89/m91 verified]
  const int crow = tm + wm * 64 + ((lane >> 4) << 2);
  const int ccol = tn + wn * 64 + lr;
#pragma unroll
  for (int m = 0; m < 4; m++) {
#pragma unroll
    for (int n = 0; n < 4; n++) {
      const int cg = ccol + n * 16;
      float bb = 0.0f;
      if (EPI != 3) bb = bias ? bias[cg] : 0.0f;
#pragma unroll
      for (int j = 0; j < 4; j++) {
        const size_t off = (size_t)(crow + m * 16 + j) * ldc + cg;
        const float v = acc[m][n][j] + bb;
        if (EPI == 0) {
          Cf[off] = v;
        } else if (EPI == 1) {
          Cf[off] += v;
        } else if (EPI == 2) {
          const float sg = __builtin_amdgcn_rcpf(
              1.0f + __builtin_amdgcn_exp2f(-1.4426950408889634f * v));
          Cb[off] = f2bf(v * sg);
        } else {
          if (cg < Nreal) Cf[off] = v;
        }
      }
    }
  }
}

// ---------------------------------------------------------------------------
// Host
// ---------------------------------------------------------------------------
extern "C" void kernel_launch(void* const* d_in, const int* in_sizes, int n_in,
                              void* d_out, int out_size, void* d_ws, size_t ws_size,
                              hipStream_t stream) {
  const int T = 2048, D = 1024, V = 50257, L = 8;
  const int M = 2 * T;       // 4096 rows
  const int Vpad = 50304;    // 393 * 128

  const int* ids = (const int*)d_in[0];
  const float* embed = (const float*)d_in[1];
  const float* norm1_w = (const float*)d_in[2];
  const float* norm2_w = (const float*)d_in[3];
  const float* a_diag = (const float*)d_in[4];
  const float* W_in = (const float*)d_in[5];
  const float* b_in = (const float*)d_in[6];
  const float* W_out = (const float*)d_in[7];
  const float* ff_w1 = (const float*)d_in[8];
  const float* ff_b1 = (const float*)d_in[9];
  const float* ff_w2 = (const float*)d_in[10];
  const float* ff_b2 = (const float*)d_in[11];
  const float* final_norm_w = (const float*)d_in[12];
  const float* lm_head_w = (const float*)d_in[13];

  // workspace carve-up
  char* w = (char*)d_ws;
  float* x = (float*)w;      w += (size_t)M * D * 4;        // f32 residual
  u16* h = (u16*)w;          w += (size_t)M * D * 2;        // bf16 norm out
  float* pre = (float*)w;    w += (size_t)M * D * 4;        // f32 scan input
  u16* hs = (u16*)w;         w += (size_t)M * D * 2;        // bf16 scan out
  u16* hff = (u16*)w;        w += (size_t)M * 2 * D * 2;    // bf16 FF mid
  u16* WinT = (u16*)w;       w += (size_t)L * D * D * 2;
  u16* WoutT = (u16*)w;      w += (size_t)L * D * D * 2;
  u16* ffw1T = (u16*)w;      w += (size_t)L * 2 * D * D * 2;
  u16* ffw2T = (u16*)w;      w += (size_t)L * 2 * D * D * 2;
  u16* lmpad = (u16*)w;      w += (size_t)Vpad * D * 2;

  // ---- weight prep (deterministic, every call) ----
  lm_cast_kernel<<<Vpad, 256, 0, stream>>>(lm_head_w, lmpad);
  transpose_cast_kernel<<<dim3(32, 32, L), dim3(32, 8), 0, stream>>>(W_in, WinT, D, D);
  transpose_cast_kernel<<<dim3(32, 32, L), dim3(32, 8), 0, stream>>>(W_out, WoutT, D, D);
  transpose_cast_kernel<<<dim3(64, 32, L), dim3(32, 8), 0, stream>>>(ff_w1, ffw1T, D, 2 * D);
  transpose_cast_kernel<<<dim3(32, 64, L), dim3(32, 8), 0, stream>>>(ff_w2, ffw2T, 2 * D, D);

  // ---- embedding ----
  embed_kernel<<<M, 256, 0, stream>>>(ids, embed, x);

  // ---- layers ----
  for (int l = 0; l < L; l++) {
    rmsnorm_kernel<<<M, 256, 0, stream>>>(x, norm1_w + (size_t)l * D, h);
    gemm_nt<0><<<dim3(8, 32), 256, 0, stream>>>(
        h, WinT + (size_t)l * D * D, b_in + (size_t)l * D, pre, nullptr,
        M, D, D, D, D);
    scan_kernel<<<8, 256, 0, stream>>>(pre, a_diag + (size_t)l * D, hs);
    gemm_nt<1><<<dim3(8, 32), 256, 0, stream>>>(
        hs, WoutT + (size_t)l * D * D, nullptr, x, nullptr,
        M, D, D, D, D);
    rmsnorm_kernel<<<M, 256, 0, stream>>>(x, norm2_w + (size_t)l * D, h);
    gemm_nt<2><<<dim3(16, 32), 256, 0, stream>>>(
        h, ffw1T + (size_t)l * 2 * D * D, ff_b1 + (size_t)l * 2 * D, nullptr, hff,
        M, 2 * D, D, 2 * D, 2 * D);
    gemm_nt<1><<<dim3(8, 32), 256, 0, stream>>>(
        hff, ffw2T + (size_t)l * 2 * D * D, ff_b2 + (size_t)l * D, x, nullptr,
        M, D, 2 * D, D, D);
  }

  // ---- final norm + lm head ----
  rmsnorm_kernel<<<M, 256, 0, stream>>>(x, final_norm_w, h);
  gemm_nt<3><<<dim3(12576), 256, 0, stream>>>(
      h, lmpad, nullptr, (float*)d_out, nullptr,
      M, Vpad, D, V, V);
}

// Round 4
// 2784.119 us; speedup vs baseline: 1.2636x; 1.1536x over previous
//
#include <hip/hip_runtime.h>

typedef unsigned short u16;
typedef __bf16 bf16x8 __attribute__((ext_vector_type(8)));
typedef float f32x4 __attribute__((ext_vector_type(4)));
typedef unsigned short u16x4 __attribute__((ext_vector_type(4)));

__device__ __forceinline__ u16 f2bf(float f) {
  union { float f; unsigned int u; } v; v.f = f;
  return (u16)((v.u + 0x7FFFu + ((v.u >> 16) & 1u)) >> 16);
}

__device__ __forceinline__ void gload16(const void* g, void* l) {
  __builtin_amdgcn_global_load_lds(
      (const __attribute__((address_space(1))) unsigned int*)g,
      (__attribute__((address_space(3))) unsigned int*)l, 16, 0, 0);
}

// ---------------------------------------------------------------------------
// Weight prep
// ---------------------------------------------------------------------------

// W (R x C f32, per-layer stride R*C) -> WT (C x R bf16)
__global__ void transpose_cast_kernel(const float* __restrict__ W, u16* __restrict__ WT,
                                      int R, int C) {
  __shared__ float tile[32][33];
  const int tx = threadIdx.x, ty = threadIdx.y;
  const size_t zoff = (size_t)blockIdx.z * R * C;
  const int c0 = blockIdx.x * 32, r0 = blockIdx.y * 32;
#pragma unroll
  for (int k = 0; k < 32; k += 8)
    tile[ty + k][tx] = W[zoff + (size_t)(r0 + ty + k) * C + (c0 + tx)];
  __syncthreads();
#pragma unroll
  for (int k = 0; k < 32; k += 8)
    WT[zoff + (size_t)(c0 + ty + k) * R + (r0 + tx)] = f2bf(tile[tx][ty + k]);
}

// lm_head (50257 x 1024 f32) -> bf16 padded to 50304 rows (pad rows zero)
__global__ void lm_cast_kernel(const float* __restrict__ lm, u16* __restrict__ out) {
  const int row = blockIdx.x;
  const int t = threadIdx.x;
  u16x4 o = {0, 0, 0, 0};
  if (row < 50257) {
    float4 v = *(const float4*)(lm + (size_t)row * 1024 + t * 4);
    o.x = f2bf(v.x); o.y = f2bf(v.y); o.z = f2bf(v.z); o.w = f2bf(v.w);
  }
  *(u16x4*)(out + (size_t)row * 1024 + t * 4) = o;
}

// ---------------------------------------------------------------------------
// Embedding gather (f32 residual stream init)
// ---------------------------------------------------------------------------
__global__ void embed_kernel(const int* __restrict__ ids, const float* __restrict__ embed,
                             float* __restrict__ x) {
  const int row = blockIdx.x;
  const int id = ids[row];
  const int t = threadIdx.x;
  *(float4*)(x + (size_t)row * 1024 + t * 4) =
      *(const float4*)(embed + (size_t)id * 1024 + t * 4);
}

// ---------------------------------------------------------------------------
// RMSNorm: f32 in -> bf16 out (D = 1024, one block per row)
// ---------------------------------------------------------------------------
__global__ void rmsnorm_kernel(const float* __restrict__ x, const float* __restrict__ w,
                               u16* __restrict__ out) {
  const int row = blockIdx.x, tid = threadIdx.x;
  const float* xr = x + (size_t)row * 1024;
  float4 v = *(const float4*)(xr + tid * 4);
  float ss = v.x * v.x + v.y * v.y + v.z * v.z + v.w * v.w;
#pragma unroll
  for (int off = 32; off; off >>= 1) ss += __shfl_xor(ss, off);
  __shared__ float red[4];
  if ((tid & 63) == 0) red[tid >> 6] = ss;
  __syncthreads();
  const float tot = red[0] + red[1] + red[2] + red[3];
  const float r = rsqrtf(tot * (1.0f / 1024.0f) + 1e-6f);
  float4 wv = *(const float4*)(w + tid * 4);
  u16x4 o;
  o.x = f2bf(v.x * r * wv.x); o.y = f2bf(v.y * r * wv.y);
  o.z = f2bf(v.z * r * wv.z); o.w = f2bf(v.w * r * wv.w);
  *(u16x4*)(out + (size_t)row * 1024 + tid * 4) = o;
}

// ---------------------------------------------------------------------------
// Sequential chaotic scan (latency-bound, ~27 us/layer)
// ---------------------------------------------------------------------------
__device__ __forceinline__ void scan_load(const float* __restrict__ p, int tb,
                                          float A2, float (&buf)[8]) {
#pragma unroll
  for (int j = 0; j < 8; j++)
    buf[j] = fmaf(p[(size_t)(tb + j) * 1024], 2.8853900817779268f, A2);
}

__device__ __forceinline__ void scan_comp(float (&buf)[8], float m2A2, float& r,
                                          u16* __restrict__ o, int tb) {
#pragma unroll
  for (int j = 0; j < 8; j++) {
    float z = fmaf(m2A2, r, buf[j]);
    float e = __builtin_amdgcn_exp2f(z);
    r = __builtin_amdgcn_rcpf(1.0f + e);
    o[(size_t)(tb + j) * 1024] = f2bf(fmaf(-2.0f, r, 1.0f));
  }
}

__global__ __launch_bounds__(256) void scan_kernel(const float* __restrict__ pre,
                                                   const float* __restrict__ a_diag,
                                                   u16* __restrict__ hs) {
  const int T = 2048;
  const int idx = blockIdx.x * 256 + threadIdx.x;  // 0..2047
  const int b = idx >> 10, d = idx & 1023;
  const float* p = pre + (size_t)b * T * 1024 + d;
  u16* o = hs + (size_t)b * T * 1024 + d;
  const float A2 = a_diag[d] * 2.8853900817779268f;
  const float m2A2 = -2.0f * A2;
  float r = 0.5f;  // s = 1 - 2r = 0
  float b0[8], b1[8], b2[8], b3[8];
  scan_load(p, 0, A2, b0); scan_load(p, 8, A2, b1);
  scan_load(p, 16, A2, b2); scan_load(p, 24, A2, b3);
  for (int t0 = 0; t0 < T; t0 += 32) {
    scan_comp(b0, m2A2, r, o, t0);
    if (t0 + 32 < T) scan_load(p, t0 + 32, A2, b0);
    scan_comp(b1, m2A2, r, o, t0 + 8);
    if (t0 + 32 < T) scan_load(p, t0 + 40, A2, b1);
    scan_comp(b2, m2A2, r, o, t0 + 16);
    if (t0 + 32 < T) scan_load(p, t0 + 48, A2, b2);
    scan_comp(b3, m2A2, r, o, t0 + 24);
    if (t0 + 32 < T) scan_load(p, t0 + 56, A2, b3);
  }
}

// ---------------------------------------------------------------------------
// gemm64: NT bf16 GEMM for layer GEMMs. C(MxN) = A(MxK) @ B(NxK)^T.
// 64x64 tile, BK=64, 4 waves (2x2 of 32x32), dbuf. Key: D
// grid = 1024 blocks = 4 blocks/CU = 16 waves/CU -> TLP hides the barrier
// drain (the 1-block/CU 128-tile exposed all latency; m114 overlap regime).
// LDS row = 64 k = 128B = 8 slots of 16B; slot ^= (row&7) -> wave-wide
// ds_read_b128 hits 64 distinct slots (conflict-free). Staging: linear LDS
// dest (gload16) + inverse-swizzled global source (rule #21).
// EPI: 0 = f32 out + bias; 1 = f32 out += v + bias; 2 = bf16 silu(v+bias)
// ---------------------------------------------------------------------------
template <int EPI>
__global__ __launch_bounds__(256) void gemm64(
    const u16* __restrict__ A, const u16* __restrict__ Bw,
    const float* __restrict__ bias, float* Cf, u16* __restrict__ Cb,
    int M, int N, int K, int ldc) {
  __shared__ char lds[32768];  // [buf][A 8K | B 8K] x 2
  const int tid = threadIdx.x;
  const int lane = tid & 63;
  const int wid = tid >> 6;
  const int wm = wid >> 1, wn = wid & 1;
  const int tm = blockIdx.y * 64, tn = blockIdx.x * 64;

  const size_t sA = (size_t)K * 2;  // global row stride (bytes)
  // staging: tid -> row tid>>3 (of 32/pass), slot tid&7; global slot pre-swizzled
  const int srow = tid >> 3;
  const int ss = (tid & 7) ^ (srow & 7);
  const char* pA = (const char*)A + (size_t)(tm + srow) * sA + (ss << 4);
  const char* pB = (const char*)Bw + (size_t)(tn + srow) * sA + (ss << 4);
  const size_t pskip = 32 * sA;  // pass 1 = +32 rows

  // fragment read offsets (A at +0, B at +8192 within buffer)
  const int lr = lane & 15;
  int aOff[2][2], bOff[2][2];
#pragma unroll
  for (int m = 0; m < 2; m++)
#pragma unroll
    for (int h = 0; h < 2; h++) {
      const int ra = wm * 32 + m * 16 + lr;
      aOff[m][h] = ra * 128 + ((((lane >> 4) + 4 * h) ^ (ra & 7)) << 4);
      const int rb = wn * 32 + m * 16 + lr;
      bOff[m][h] = 8192 + rb * 128 + ((((lane >> 4) + 4 * h) ^ (rb & 7)) << 4);
    }

  f32x4 acc[2][2] = {};

  {  // prologue: stage first K-tile into buf 0
    char* d = lds + tid * 16;
    gload16(pA, d);
    gload16(pA + pskip, d + 4096);
    gload16(pB, d + 8192);
    gload16(pB + pskip, d + 12288);
  }
  __syncthreads();

  int cur = 0;
  for (int k0 = 0; k0 < K; k0 += 64) {
    if (k0 + 64 < K) {
      const size_t kb = (size_t)(k0 + 64) * 2;
      char* d = lds + (cur ^ 1) * 16384 + tid * 16;
      gload16(pA + kb, d);
      gload16(pA + pskip + kb, d + 4096);
      gload16(pB + kb, d + 8192);
      gload16(pB + pskip + kb, d + 12288);
    }
    const char* base = lds + cur * 16384;
    bf16x8 aF[2][2], bF[2][2];
#pragma unroll
    for (int m = 0; m < 2; m++)
#pragma unroll
      for (int h = 0; h < 2; h++) {
        aF[m][h] = *(const bf16x8*)(base + aOff[m][h]);
        bF[m][h] = *(const bf16x8*)(base + bOff[m][h]);
      }
#pragma unroll
    for (int h = 0; h < 2; h++)
#pragma unroll
      for (int m = 0; m < 2; m++)
#pragma unroll
        for (int n = 0; n < 2; n++)
          acc[m][n] = __builtin_amdgcn_mfma_f32_16x16x32_bf16(aF[m][h], bF[n][h],
                                                              acc[m][n], 0, 0, 0);
    __syncthreads();
    cur ^= 1;
  }

  // C/D layout: col = lane&15, row = (lane>>4)*4 + j
  const int crow = tm + wm * 32 + ((lane >> 4) << 2);
  const int ccol = tn + wn * 32 + lr;
#pragma unroll
  for (int m = 0; m < 2; m++) {
#pragma unroll
    for (int n = 0; n < 2; n++) {
      const int cg = ccol + n * 16;
      const float bb = bias ? bias[cg] : 0.0f;
#pragma unroll
      for (int j = 0; j < 4; j++) {
        const size_t off = (size_t)(crow + m * 16 + j) * ldc + cg;
        const float v = acc[m][n][j] + bb;
        if (EPI == 0) {
          Cf[off] = v;
        } else if (EPI == 1) {
          Cf[off] += v;
        } else {
          const float sg = __builtin_amdgcn_rcpf(
              1.0f + __builtin_amdgcn_exp2f(-1.4426950408889634f * v));
          Cb[off] = f2bf(v * sg);
        }
      }
    }
  }
}

// ---------------------------------------------------------------------------
// lm-head GEMM: 128x128 tile, BK=32, 4 waves, dbuf (as before).
// Grid map: each col-tile handled by 32 consecutive bids (4 per XCD via HW
// bid%8 round-robin) -> all 8 XCDs walk the SAME B col-tile window in
// lockstep; B (103MB) streams from HBM ~once via L3, each XCD holds its
// 1MB A-slice (4 row-tiles) in L2.
// ---------------------------------------------------------------------------
__global__ __launch_bounds__(256) void gemm_lm(
    const u16* __restrict__ A, const u16* __restrict__ Bw,
    float* __restrict__ Cf, int K, int ldc, int Nreal) {
  __shared__ char lds[32768];
  const int tid = threadIdx.x;
  const int lane = tid & 63;
  const int wid = tid >> 6;
  const int wm = wid >> 1, wn = wid & 1;
  const int bid = blockIdx.x;
  const int tm = (((bid & 7) << 2) + ((bid >> 3) & 3)) * 128;  // XCD owns 4 row tiles
  const int tn = (bid >> 5) * 128;                             // col advances /32 bids

  const size_t sA = (size_t)K * 2;
  const int r0 = tid >> 2;
  const int slot = (tid & 3) ^ ((tid >> 3) & 3);
  const char* pA = (const char*)A + (size_t)(tm + r0) * sA + (slot << 4);
  const char* pB = (const char*)Bw + (size_t)(tn + r0) * sA + (slot << 4);
  const size_t rowskip = 64 * sA;

  const int lr = lane & 15;
  const int rdoff = ((lane >> 4) << 4) ^ (((lr >> 1) & 3) << 4);
  int aOff[4], bOff[4];
#pragma unroll
  for (int m = 0; m < 4; m++) aOff[m] = (wm * 64 + m * 16 + lr) * 64 + rdoff;
#pragma unroll
  for (int n = 0; n < 4; n++) bOff[n] = 8192 + (wn * 64 + n * 16 + lr) * 64 + rdoff;

  f32x4 acc[4][4] = {};

  {
    char* dA = lds + tid * 16;
    gload16(pA, dA);
    gload16(pA + rowskip, dA + 4096);
    gload16(pB, dA + 8192);
    gload16(pB + rowskip, dA + 12288);
  }
  __syncthreads();

  int cur = 0;
  for (int k0 = 0; k0 < K; k0 += 32) {
    if (k0 + 32 < K) {
      const size_t kb = (size_t)(k0 + 32) * 2;
      char* dA = lds + (cur ^ 1) * 16384 + tid * 16;
      gload16(pA + kb, dA);
      gload16(pA + rowskip + kb, dA + 4096);
      gload16(pB + kb, dA + 8192);
      gload16(pB + rowskip + kb, dA + 12288);
    }
    const char* base = lds + cur * 16384;
    bf16x8 af[4], bfr[4];
#pragma unroll
    for (int m = 0; m < 4; m++) af[m] = *(const bf16x8*)(base + aOff[m]);
#pragma unroll
    for (int n = 0; n < 4; n++) bfr[n] = *(const bf16x8*)(base + bOff[n]);
#pragma unroll
    for (int m = 0; m < 4; m++)
#pragma unroll
      for (int n = 0; n < 4; n++)
        acc[m][n] =
            __builtin_amdgcn_mfma_f32_16x16x32_bf16(af[m], bfr[n], acc[m][n], 0, 0, 0);
    __syncthreads();
    cur ^= 1;
  }

  const int crow = tm + wm * 64 + ((lane >> 4) << 2);
  const int ccol = tn + wn * 64 + lr;
#pragma unroll
  for (int m = 0; m < 4; m++) {
#pragma unroll
    for (int n = 0; n < 4; n++) {
      const int cg = ccol + n * 16;
#pragma unroll
      for (int j = 0; j < 4; j++) {
        if (cg < Nreal)
          Cf[(size_t)(crow + m * 16 + j) * ldc + cg] = acc[m][n][j];
      }
    }
  }
}

// ---------------------------------------------------------------------------
// Host
// ---------------------------------------------------------------------------
extern "C" void kernel_launch(void* const* d_in, const int* in_sizes, int n_in,
                              void* d_out, int out_size, void* d_ws, size_t ws_size,
                              hipStream_t stream) {
  const int T = 2048, D = 1024, V = 50257, L = 8;
  const int M = 2 * T;       // 4096 rows
  const int Vpad = 50304;    // 393 * 128

  const int* ids = (const int*)d_in[0];
  const float* embed = (const float*)d_in[1];
  const float* norm1_w = (const float*)d_in[2];
  const float* norm2_w = (const float*)d_in[3];
  const float* a_diag = (const float*)d_in[4];
  const float* W_in = (const float*)d_in[5];
  const float* b_in = (const float*)d_in[6];
  const float* W_out = (const float*)d_in[7];
  const float* ff_w1 = (const float*)d_in[8];
  const float* ff_b1 = (const float*)d_in[9];
  const float* ff_w2 = (const float*)d_in[10];
  const float* ff_b2 = (const float*)d_in[11];
  const float* final_norm_w = (const float*)d_in[12];
  const float* lm_head_w = (const float*)d_in[13];

  // workspace carve-up
  char* w = (char*)d_ws;
  float* x = (float*)w;      w += (size_t)M * D * 4;        // f32 residual
  u16* h = (u16*)w;          w += (size_t)M * D * 2;        // bf16 norm out
  float* pre = (float*)w;    w += (size_t)M * D * 4;        // f32 scan input
  u16* hs = (u16*)w;         w += (size_t)M * D * 2;        // bf16 scan out
  u16* hff = (u16*)w;        w += (size_t)M * 2 * D * 2;    // bf16 FF mid
  u16* WinT = (u16*)w;       w += (size_t)L * D * D * 2;
  u16* WoutT = (u16*)w;      w += (size_t)L * D * D * 2;
  u16* ffw1T = (u16*)w;      w += (size_t)L * 2 * D * D * 2;
  u16* ffw2T = (u16*)w;      w += (size_t)L * 2 * D * D * 2;
  u16* lmpad = (u16*)w;      w += (size_t)Vpad * D * 2;

  // ---- weight prep (deterministic, every call) ----
  lm_cast_kernel<<<Vpad, 256, 0, stream>>>(lm_head_w, lmpad);
  transpose_cast_kernel<<<dim3(32, 32, L), dim3(32, 8), 0, stream>>>(W_in, WinT, D, D);
  transpose_cast_kernel<<<dim3(32, 32, L), dim3(32, 8), 0, stream>>>(W_out, WoutT, D, D);
  transpose_cast_kernel<<<dim3(64, 32, L), dim3(32, 8), 0, stream>>>(ff_w1, ffw1T, D, 2 * D);
  transpose_cast_kernel<<<dim3(32, 64, L), dim3(32, 8), 0, stream>>>(ff_w2, ffw2T, 2 * D, D);

  // ---- embedding ----
  embed_kernel<<<M, 256, 0, stream>>>(ids, embed, x);

  // ---- layers ----
  for (int l = 0; l < L; l++) {
    rmsnorm_kernel<<<M, 256, 0, stream>>>(x, norm1_w + (size_t)l * D, h);
    gemm64<0><<<dim3(16, 64), 256, 0, stream>>>(
        h, WinT + (size_t)l * D * D, b_in + (size_t)l * D, pre, nullptr,
        M, D, D, D);
    scan_kernel<<<8, 256, 0, stream>>>(pre, a_diag + (size_t)l * D, hs);
    gemm64<1><<<dim3(16, 64), 256, 0, stream>>>(
        hs, WoutT + (size_t)l * D * D, nullptr, x, nullptr,
        M, D, D, D);
    rmsnorm_kernel<<<M, 256, 0, stream>>>(x, norm2_w + (size_t)l * D, h);
    gemm64<2><<<dim3(32, 64), 256, 0, stream>>>(
        h, ffw1T + (size_t)l * 2 * D * D, ff_b1 + (size_t)l * 2 * D, nullptr, hff,
        M, 2 * D, D, 2 * D);
    gemm64<1><<<dim3(16, 64), 256, 0, stream>>>(
        hff, ffw2T + (size_t)l * 2 * D * D, ff_b2 + (size_t)l * D, x, nullptr,
        M, D, 2 * D, D);
  }

  // ---- final norm + lm head ----
  rmsnorm_kernel<<<M, 256, 0, stream>>>(x, final_norm_w, h);
  gemm_lm<<<dim3(12576), 256, 0, stream>>>(h, lmpad, (float*)d_out, D, V, V);
}